// Round 1
// baseline (706.513 us; speedup 1.0000x reference)
//
#include <hip/hip_runtime.h>
#include <hip/hip_bf16.h>
#include <math.h>

#define BB 2
#define SS 2048
#define EE 2048
#define HH 16
#define DD 128
#define MM (BB*SS)

typedef __attribute__((ext_vector_type(8))) short bf16x8;
typedef __attribute__((ext_vector_type(4))) float f32x4;

__device__ inline float bf2f(const __hip_bfloat16 h){ return __bfloat162float(h); }
__device__ inline __hip_bfloat16 f2bf(float f){ return __float2bfloat16(f); }
__device__ inline short f2bs(float f){
  union { __hip_bfloat16 h; short s; } u; u.h = __float2bfloat16(f); return u.s;
}

__device__ inline void gload16(const void* g, void* l){
  __builtin_amdgcn_global_load_lds((const __attribute__((address_space(1))) void*)g,
      (__attribute__((address_space(3))) void*)l, 16, 0, 0);
}

// ---------------- fp32 -> bf16 convert, 4 elems/thread ----------------
__global__ void cvt_kernel(const float* __restrict__ in, __hip_bfloat16* __restrict__ out, int n4){
  int i = blockIdx.x*256 + threadIdx.x;
  if (i >= n4) return;
  float4 v = ((const float4*)in)[i];
  union { short4 s4; short s[4]; } u;
  u.s[0] = f2bs(v.x); u.s[1] = f2bs(v.y); u.s[2] = f2bs(v.z); u.s[3] = f2bs(v.w);
  ((short4*)out)[i] = u.s4;
}

// ---------------- RoPE tables (double precision, one-time) ----------------
__global__ void rope_tables_kernel(float* __restrict__ cost, float* __restrict__ sint){
  int idx = blockIdx.x*256 + threadIdx.x;  // SS*64
  int s = idx >> 6, i = idx & 63;
  double inv = exp(-log(10000.0) * (double)i / 64.0);
  double f = (double)s * inv;
  cost[idx] = (float)cos(f);
  sint[idx] = (float)sin(f);
}

// ---------------- RoPE apply on q,k (bf16, in place) ----------------
__global__ void rope_kernel(__hip_bfloat16* __restrict__ q, __hip_bfloat16* __restrict__ k,
                            const float* __restrict__ cost, const float* __restrict__ sint){
  int idx = blockIdx.x*256 + threadIdx.x;   // BB*SS*HH*64
  int i = idx & 63;
  int h = (idx >> 6) & (HH-1);
  int bs = idx >> 10;          // b*SS + s
  int s = bs & (SS-1);
  float c = cost[s*64 + i], sn = sint[s*64 + i];
  size_t base = ((size_t)bs*HH + h)*DD + i;
  float q1 = bf2f(q[base]), q2 = bf2f(q[base+64]);
  q[base]    = f2bf(q1*c - q2*sn);
  q[base+64] = f2bf(q2*c + q1*sn);
  float k1 = bf2f(k[base]), k2 = bf2f(k[base+64]);
  k[base]    = f2bf(k1*c - k2*sn);
  k[base+64] = f2bf(k2*c + k1*sn);
}

// ---------------- bf16 GEMM: C[m][f] = sum_e A[m][e] * W[f][e] + bias[f] ----------------
// MODE 0: write bf16 C[m*EE+f]   (q,k)
// MODE 1: write bf16 transposed vt[(b*EE+f)*SS+s]  (v)
// MODE 2: write fp32 C[m*EE+f]   (final out)
template<int MODE>
__global__ __launch_bounds__(256) void gemm_bt(const __hip_bfloat16* __restrict__ A,
                        const __hip_bfloat16* __restrict__ Bw,
                        const float* __restrict__ bias, void* __restrict__ Cout){
  __shared__ short As[128*32];
  __shared__ short Bs[128*32];
  const int tid = threadIdx.x;
  const int wid = tid >> 6, lane = tid & 63;
  const int g = lane >> 4, c16 = lane & 15;
  const int wm = wid >> 1, wn = wid & 1;
  const int rowA0 = blockIdx.x*128, colB0 = blockIdx.y*128;
  const int K = EE;

  f32x4 acc[4][4] = {};

  for (int k0 = 0; k0 < K; k0 += 32) {
    __syncthreads();
    #pragma unroll
    for (int it = 0; it < 2; ++it) {
      int cbase = it*256 + wid*64;           // wave-uniform chunk base
      int c = cbase + lane;
      int r = c >> 2, ko = (c & 3) << 3;
      gload16(&A [(size_t)(rowA0 + r)*K + k0 + ko], &As[cbase*8]);
      gload16(&Bw[(size_t)(colB0 + r)*K + k0 + ko], &Bs[cbase*8]);
    }
    __syncthreads();
    bf16x8 af[4], bfr[4];
    #pragma unroll
    for (int mi=0;mi<4;mi++) af[mi]  = *(const bf16x8*)&As[(wm*64 + mi*16 + c16)*32 + g*8];
    #pragma unroll
    for (int ni=0;ni<4;ni++) bfr[ni] = *(const bf16x8*)&Bs[(wn*64 + ni*16 + c16)*32 + g*8];
    #pragma unroll
    for (int mi=0;mi<4;mi++)
      #pragma unroll
      for (int ni=0;ni<4;ni++)
        acc[mi][ni] = __builtin_amdgcn_mfma_f32_16x16x32_bf16(af[mi], bfr[ni], acc[mi][ni], 0,0,0);
  }

  #pragma unroll
  for (int mi=0;mi<4;mi++){
    #pragma unroll
    for (int ni=0;ni<4;ni++){
      int f = colB0 + wn*64 + ni*16 + c16;
      float bv = bias[f];
      #pragma unroll
      for (int j=0;j<4;j++){
        int m = rowA0 + wm*64 + mi*16 + g*4 + j;
        float v = acc[mi][ni][j] + bv;
        if constexpr (MODE == 0) {
          ((__hip_bfloat16*)Cout)[(size_t)m*EE + f] = f2bf(v);
        } else if constexpr (MODE == 1) {
          int b = m >> 11, s = m & (SS-1);
          ((__hip_bfloat16*)Cout)[((size_t)(b*EE + f))*SS + s] = f2bf(v);
        } else {
          ((float*)Cout)[(size_t)m*EE + f] = v;
        }
      }
    }
  }
}

// ---------------- flash attention (causal), 64 q-rows/block, 4 waves ----------------
__global__ __launch_bounds__(256) void attn_kernel(const __hip_bfloat16* __restrict__ qg,
    const __hip_bfloat16* __restrict__ kg, const __hip_bfloat16* __restrict__ vtg,
    __hip_bfloat16* __restrict__ og){
  __shared__ short P[4][16][40];   // per-wave P tile, row stride 80B (16B aligned, ~2-way banks)
  const int tid=threadIdx.x, wid=tid>>6, lane=tid&63, g=lane>>4, c16=lane&15;
  const int qt = blockIdx.x, bh = blockIdx.y, b = bh>>4, h = bh&15;
  const int q0 = qt*64, qw = q0 + wid*16;
  const __hip_bfloat16* qbase = qg + ((size_t)b*SS)*EE + h*DD;
  const __hip_bfloat16* kbase = kg + ((size_t)b*SS)*EE + h*DD;
  const __hip_bfloat16* vbase = vtg + ((size_t)bh)*DD*SS;

  bf16x8 qf[4];
  #pragma unroll
  for (int ds=0; ds<4; ds++)
    qf[ds] = *(const bf16x8*)&qbase[(size_t)(qw + c16)*EE + ds*32 + g*8];

  f32x4 oacc[8] = {};
  float mrun[4], lrun[4];
  #pragma unroll
  for (int j=0;j<4;j++){ mrun[j] = -INFINITY; lrun[j] = 0.f; }
  const float SCL = 0.08838834764831845f * 1.4426950408889634f;  // 1/sqrt(128) * log2(e)
  const int nkv = q0 + 64;

  for (int kv0 = 0; kv0 < nkv; kv0 += 32) {
    f32x4 sacc[2] = {};
    #pragma unroll
    for (int kvf=0; kvf<2; kvf++)
      #pragma unroll
      for (int ds=0; ds<4; ds++){
        bf16x8 kf = *(const bf16x8*)&kbase[(size_t)(kv0 + kvf*16 + c16)*EE + ds*32 + g*8];
        sacc[kvf] = __builtin_amdgcn_mfma_f32_16x16x32_bf16(qf[ds], kf, sacc[kvf], 0,0,0);
      }

    const bool domask = (kv0 + 31 > qw);
    float mt[4], pr0[4], pr1[4], rs[4];
    #pragma unroll
    for (int j=0;j<4;j++){
      float v0 = sacc[0][j], v1 = sacc[1][j];
      if (domask){
        int qrow = qw + g*4 + j;
        if (kv0 + c16 > qrow)      v0 = -INFINITY;
        if (kv0 + 16 + c16 > qrow) v1 = -INFINITY;
      }
      sacc[0][j] = v0; sacc[1][j] = v1;
      float m = fmaxf(v0, v1);
      #pragma unroll
      for (int off=8; off>=1; off>>=1) m = fmaxf(m, __shfl_xor(m, off, 16));
      mt[j] = m;
    }
    #pragma unroll
    for (int j=0;j<4;j++){
      float mnew = fmaxf(mrun[j], mt[j]);
      rs[j] = exp2f((mrun[j] - mnew)*SCL);
      mrun[j] = mnew;
      pr0[j] = exp2f((sacc[0][j]-mnew)*SCL);
      pr1[j] = exp2f((sacc[1][j]-mnew)*SCL);
      float ps = pr0[j] + pr1[j];
      #pragma unroll
      for (int off=8; off>=1; off>>=1) ps += __shfl_xor(ps, off, 16);
      lrun[j] = lrun[j]*rs[j] + ps;
    }
    #pragma unroll
    for (int dc=0; dc<8; dc++){
      f32x4 o = oacc[dc];
      o[0]*=rs[0]; o[1]*=rs[1]; o[2]*=rs[2]; o[3]*=rs[3];
      oacc[dc] = o;
    }
    // P -> LDS (per-wave private; wave-lockstep + compiler lgkmcnt handles ordering)
    #pragma unroll
    for (int j=0;j<4;j++){
      P[wid][g*4+j][c16]    = f2bs(pr0[j]);
      P[wid][g*4+j][16+c16] = f2bs(pr1[j]);
    }
    bf16x8 pf = *(const bf16x8*)&P[wid][c16][g*8];
    #pragma unroll
    for (int dc=0; dc<8; dc++){
      bf16x8 vf = *(const bf16x8*)&vbase[(size_t)(dc*16 + c16)*SS + kv0 + g*8];
      oacc[dc] = __builtin_amdgcn_mfma_f32_16x16x32_bf16(pf, vf, oacc[dc], 0,0,0);
    }
  }

  float inv[4];
  #pragma unroll
  for (int j=0;j<4;j++) inv[j] = 1.0f / lrun[j];
  #pragma unroll
  for (int dc=0; dc<8; dc++)
    #pragma unroll
    for (int j=0;j<4;j++)
      og[((size_t)(b*SS + qw + g*4 + j))*EE + h*DD + dc*16 + c16] = f2bf(oacc[dc][j]*inv[j]);
}

extern "C" void kernel_launch(void* const* d_in, const int* in_sizes, int n_in,
                              void* d_out, int out_size, void* d_ws, size_t ws_size,
                              hipStream_t stream){
  const float* x  = (const float*)d_in[0];
  const float* Wq = (const float*)d_in[1];
  const float* bq = (const float*)d_in[2];
  const float* Wk = (const float*)d_in[3];
  const float* bk = (const float*)d_in[4];
  const float* Wv = (const float*)d_in[5];
  const float* bv = (const float*)d_in[6];
  const float* Wp = (const float*)d_in[7];
  const float* bp = (const float*)d_in[8];
  float* out = (float*)d_out;

  char* ws = (char*)d_ws;
  size_t off = 0;
  auto alloc = [&](size_t bytes){ void* p = ws + off; off += (bytes + 255) & ~(size_t)255; return p; };
  const size_t nx = (size_t)MM*EE;   // 8.39M elems
  const size_t nw = (size_t)EE*EE;   // 4.19M elems
  __hip_bfloat16* xb  = (__hip_bfloat16*)alloc(nx*2);
  __hip_bfloat16* wqb = (__hip_bfloat16*)alloc(nw*2);
  __hip_bfloat16* wkb = (__hip_bfloat16*)alloc(nw*2);
  __hip_bfloat16* wvb = (__hip_bfloat16*)alloc(nw*2);
  __hip_bfloat16* wpb = (__hip_bfloat16*)alloc(nw*2);
  __hip_bfloat16* qb  = (__hip_bfloat16*)alloc(nx*2);
  __hip_bfloat16* kb  = (__hip_bfloat16*)alloc(nx*2);
  __hip_bfloat16* vtb = (__hip_bfloat16*)alloc(nx*2);
  __hip_bfloat16* ob  = (__hip_bfloat16*)alloc(nx*2);
  float* cost = (float*)alloc((size_t)SS*64*4);
  float* sint = (float*)alloc((size_t)SS*64*4);

  cvt_kernel<<<(int)(nx/4/256), 256, 0, stream>>>(x,  xb,  (int)(nx/4));
  cvt_kernel<<<(int)(nw/4/256), 256, 0, stream>>>(Wq, wqb, (int)(nw/4));
  cvt_kernel<<<(int)(nw/4/256), 256, 0, stream>>>(Wk, wkb, (int)(nw/4));
  cvt_kernel<<<(int)(nw/4/256), 256, 0, stream>>>(Wv, wvb, (int)(nw/4));
  cvt_kernel<<<(int)(nw/4/256), 256, 0, stream>>>(Wp, wpb, (int)(nw/4));
  rope_tables_kernel<<<SS*64/256, 256, 0, stream>>>(cost, sint);

  dim3 gg(MM/128, EE/128);
  gemm_bt<0><<<gg, 256, 0, stream>>>(xb, wqb, bq, qb);
  gemm_bt<0><<<gg, 256, 0, stream>>>(xb, wkb, bk, kb);
  gemm_bt<1><<<gg, 256, 0, stream>>>(xb, wvb, bv, vtb);

  rope_kernel<<<(BB*SS*HH*64)/256, 256, 0, stream>>>(qb, kb, cost, sint);

  attn_kernel<<<dim3(SS/64, BB*HH), 256, 0, stream>>>(qb, kb, vtb, ob);

  gemm_bt<2><<<gg, 256, 0, stream>>>(ob, wpb, bp, out);
}

// Round 2
// 333.372 us; speedup vs baseline: 2.1193x; 2.1193x over previous
//
#include <hip/hip_runtime.h>
#include <hip/hip_bf16.h>
#include <math.h>

#define BB 2
#define SS 2048
#define EE 2048
#define HH 16
#define DD 128
#define MM (BB*SS)

typedef __attribute__((ext_vector_type(8))) short bf16x8;
typedef __attribute__((ext_vector_type(4))) float f32x4;

__device__ inline float bf2f(const __hip_bfloat16 h){ return __bfloat162float(h); }
__device__ inline __hip_bfloat16 f2bf(float f){ return __float2bfloat16(f); }
__device__ inline short f2bs(float f){
  union { __hip_bfloat16 h; short s; } u; u.h = __float2bfloat16(f); return u.s;
}

__device__ inline void gload16(const void* g, void* l){
  __builtin_amdgcn_global_load_lds((const __attribute__((address_space(1))) void*)g,
      (__attribute__((address_space(3))) void*)l, 16, 0, 0);
}

// ---------------- fp32 -> bf16 convert, 4 elems/thread ----------------
__global__ void cvt_kernel(const float* __restrict__ in, __hip_bfloat16* __restrict__ out, int n4){
  int i = blockIdx.x*256 + threadIdx.x;
  if (i >= n4) return;
  float4 v = ((const float4*)in)[i];
  union { short4 s4; short s[4]; } u;
  u.s[0] = f2bs(v.x); u.s[1] = f2bs(v.y); u.s[2] = f2bs(v.z); u.s[3] = f2bs(v.w);
  ((short4*)out)[i] = u.s4;
}

// ---------------- RoPE tables (double precision, one-time) ----------------
__global__ void rope_tables_kernel(float* __restrict__ cost, float* __restrict__ sint){
  int idx = blockIdx.x*256 + threadIdx.x;  // SS*64
  int s = idx >> 6, i = idx & 63;
  double inv = exp(-log(10000.0) * (double)i / 64.0);
  double f = (double)s * inv;
  cost[idx] = (float)cos(f);
  sint[idx] = (float)sin(f);
}

// ---------------- RoPE apply on q,k (bf16, in place) ----------------
__global__ void rope_kernel(__hip_bfloat16* __restrict__ q, __hip_bfloat16* __restrict__ k,
                            const float* __restrict__ cost, const float* __restrict__ sint){
  int idx = blockIdx.x*256 + threadIdx.x;   // BB*SS*HH*64
  int i = idx & 63;
  int h = (idx >> 6) & (HH-1);
  int bs = idx >> 10;          // b*SS + s
  int s = bs & (SS-1);
  float c = cost[s*64 + i], sn = sint[s*64 + i];
  size_t base = ((size_t)bs*HH + h)*DD + i;
  float q1 = bf2f(q[base]), q2 = bf2f(q[base+64]);
  q[base]    = f2bf(q1*c - q2*sn);
  q[base+64] = f2bf(q2*c + q1*sn);
  float k1 = bf2f(k[base]), k2 = bf2f(k[base+64]);
  k[base]    = f2bf(k1*c - k2*sn);
  k[base+64] = f2bf(k2*c + k1*sn);
}

// ---------------- bf16 GEMM: C[m][f] = sum_e A[m][e] * W[f][e] + bias[f] ----------------
template<int MODE>
__global__ __launch_bounds__(256) void gemm_bt(const __hip_bfloat16* __restrict__ A,
                        const __hip_bfloat16* __restrict__ Bw,
                        const float* __restrict__ bias, void* __restrict__ Cout){
  __shared__ short As[128*32];
  __shared__ short Bs[128*32];
  const int tid = threadIdx.x;
  const int wid = tid >> 6, lane = tid & 63;
  const int g = lane >> 4, c16 = lane & 15;
  const int wm = wid >> 1, wn = wid & 1;
  const int rowA0 = blockIdx.x*128, colB0 = blockIdx.y*128;
  const int K = EE;

  f32x4 acc[4][4] = {};

  for (int k0 = 0; k0 < K; k0 += 32) {
    __syncthreads();
    #pragma unroll
    for (int it = 0; it < 2; ++it) {
      int cbase = it*256 + wid*64;           // wave-uniform chunk base
      int c = cbase + lane;
      int r = c >> 2, ko = (c & 3) << 3;
      gload16(&A [(size_t)(rowA0 + r)*K + k0 + ko], &As[cbase*8]);
      gload16(&Bw[(size_t)(colB0 + r)*K + k0 + ko], &Bs[cbase*8]);
    }
    __syncthreads();
    bf16x8 af[4], bfr[4];
    #pragma unroll
    for (int mi=0;mi<4;mi++) af[mi]  = *(const bf16x8*)&As[(wm*64 + mi*16 + c16)*32 + g*8];
    #pragma unroll
    for (int ni=0;ni<4;ni++) bfr[ni] = *(const bf16x8*)&Bs[(wn*64 + ni*16 + c16)*32 + g*8];
    #pragma unroll
    for (int mi=0;mi<4;mi++)
      #pragma unroll
      for (int ni=0;ni<4;ni++)
        acc[mi][ni] = __builtin_amdgcn_mfma_f32_16x16x32_bf16(af[mi], bfr[ni], acc[mi][ni], 0,0,0);
  }

  #pragma unroll
  for (int mi=0;mi<4;mi++){
    #pragma unroll
    for (int ni=0;ni<4;ni++){
      int f = colB0 + wn*64 + ni*16 + c16;
      float bv = bias[f];
      #pragma unroll
      for (int j=0;j<4;j++){
        int m = rowA0 + wm*64 + mi*16 + g*4 + j;
        float v = acc[mi][ni][j] + bv;
        if constexpr (MODE == 0) {
          ((__hip_bfloat16*)Cout)[(size_t)m*EE + f] = f2bf(v);
        } else if constexpr (MODE == 1) {
          int b = m >> 11, s = m & (SS-1);
          ((__hip_bfloat16*)Cout)[((size_t)(b*EE + f))*SS + s] = f2bf(v);
        } else {
          ((float*)Cout)[(size_t)m*EE + f] = v;
        }
      }
    }
  }
}

// ---------------- flash attention (causal), 4 waves, QBLK=64, KVBLK=64 ----------------
// Block bq processes q-tiles (31-bq) and bq -> constant 33 kv-iters per block.
// K tile [64][128] and Vt tile [128][64] double-buffered in LDS, XOR-swizzled
// (linear LDS dest for global_load_lds; swizzle applied on the GLOBAL source
// address + on the ds_read address — rule #21 both-sides pattern).
__global__ __launch_bounds__(256) void attn_kernel(const __hip_bfloat16* __restrict__ qg,
    const __hip_bfloat16* __restrict__ kg, const __hip_bfloat16* __restrict__ vtg,
    __hip_bfloat16* __restrict__ og){
  __shared__ short Ks[2][64*128];    // 16KB each
  __shared__ short Vs[2][128*64];    // 16KB each
  __shared__ short Pl[4][16*76];     // per-wave P tile, stride 76 shorts (152B)
  const int tid=threadIdx.x, wid=tid>>6, lane=tid&63, g=lane>>4, c16=lane&15;
  const int bq = blockIdx.x, bh = blockIdx.y, b = bh>>4, h = bh&15;
  const char* kb8 = (const char*)(kg + ((size_t)b*SS)*EE + h*DD);
  const char* vb8 = (const char*)(vtg + (size_t)bh*DD*SS);
  const __hip_bfloat16* qbase = qg + ((size_t)b*SS)*EE + h*DD;
  const float SCL = 0.08838834764831845f * 1.4426950408889634f;  // 1/sqrt(128)*log2(e)

  #pragma unroll 1
  for (int t = 0; t < 2; ++t){
    const int qtile = t ? bq : (31 - bq);
    const int q0 = qtile*64, qw = q0 + wid*16;
    const int niter = qtile + 1;

    bf16x8 qf[4];
    #pragma unroll
    for (int ds=0; ds<4; ds++)
      qf[ds] = *(const bf16x8*)&qbase[(size_t)(qw + c16)*EE + ds*32 + g*8];

    f32x4 oacc[8] = {};
    float mrun[4], lrun[4];
    #pragma unroll
    for (int j=0;j<4;j++){ mrun[j] = -INFINITY; lrun[j] = 0.f; }

    // ---- stage tile 0 into buffer 0 ----
    #pragma unroll
    for (int i=0;i<4;i++){
      int base = i*4096 + wid*1024;
      int lb = base + lane*16;
      int r = lb >> 8, cb = lb & 255;
      gload16(kb8 + (size_t)r*4096 + (cb ^ ((r&7)<<4)), (char*)Ks[0] + base);
    }
    #pragma unroll
    for (int i=0;i<4;i++){
      int base = i*4096 + wid*1024;
      int lb = base + lane*16;
      int d = lb >> 7, cb = lb & 127;
      gload16(vb8 + (size_t)d*4096 + (cb ^ ((d&7)<<4)), (char*)Vs[0] + base);
    }
    __syncthreads();

    int cur = 0;
    #pragma unroll 1
    for (int it = 0; it < niter; ++it){
      const int kv0 = it*64;
      // ---- prefetch next tile into buf^1 ----
      if (it + 1 < niter){
        const int kn = kv0 + 64;
        #pragma unroll
        for (int i=0;i<4;i++){
          int base = i*4096 + wid*1024;
          int lb = base + lane*16;
          int r = lb >> 8, cb = lb & 255;
          gload16(kb8 + (size_t)(kn + r)*4096 + (cb ^ ((r&7)<<4)), (char*)Ks[cur^1] + base);
        }
        #pragma unroll
        for (int i=0;i<4;i++){
          int base = i*4096 + wid*1024;
          int lb = base + lane*16;
          int d = lb >> 7, cb = lb & 127;
          gload16(vb8 + (size_t)d*4096 + (size_t)kn*2 + (cb ^ ((d&7)<<4)), (char*)Vs[cur^1] + base);
        }
      }

      // ---- QK^T : S[16q x 64kv] per wave ----
      f32x4 sacc[4] = {};
      #pragma unroll
      for (int kq=0; kq<4; kq++){
        int row = kq*16 + c16;
        int rsw = (c16 & 7) << 4;
        #pragma unroll
        for (int ds=0; ds<4; ds++){
          bf16x8 kf = *(const bf16x8*)((const char*)Ks[cur] + row*256 + ((ds*64 + g*16) ^ rsw));
          sacc[kq] = __builtin_amdgcn_mfma_f32_16x16x32_bf16(qf[ds], kf, sacc[kq], 0,0,0);
        }
      }

      // ---- causal mask (diagonal tile only) ----
      if (kv0 + 63 > qw){
        #pragma unroll
        for (int kq=0; kq<4; kq++)
          #pragma unroll
          for (int j=0;j<4;j++)
            if (kv0 + kq*16 + c16 > qw + g*4 + j) sacc[kq][j] = -INFINITY;
      }

      // ---- online softmax (rows in lane-groups of 16) ----
      float pr[4][4], rs[4];
      #pragma unroll
      for (int j=0;j<4;j++){
        float m = fmaxf(fmaxf(sacc[0][j], sacc[1][j]), fmaxf(sacc[2][j], sacc[3][j]));
        #pragma unroll
        for (int off=8; off>=1; off>>=1) m = fmaxf(m, __shfl_xor(m, off, 16));
        float mnew = fmaxf(mrun[j], m);
        rs[j] = exp2f((mrun[j] - mnew)*SCL);
        mrun[j] = mnew;
        float ps = 0.f;
        #pragma unroll
        for (int kq=0; kq<4; kq++){
          pr[kq][j] = exp2f((sacc[kq][j] - mnew)*SCL);
          ps += pr[kq][j];
        }
        #pragma unroll
        for (int off=8; off>=1; off>>=1) ps += __shfl_xor(ps, off, 16);
        lrun[j] = lrun[j]*rs[j] + ps;
      }
      #pragma unroll
      for (int dc=0; dc<8; dc++){
        f32x4 o = oacc[dc];
        o[0]*=rs[0]; o[1]*=rs[1]; o[2]*=rs[2]; o[3]*=rs[3];
        oacc[dc] = o;
      }

      // ---- P -> LDS (per-wave private) -> A-fragments ----
      #pragma unroll
      for (int j=0;j<4;j++)
        #pragma unroll
        for (int kq=0; kq<4; kq++)
          Pl[wid][(g*4+j)*76 + kq*16 + c16] = f2bs(pr[kq][j]);
      bf16x8 pf[2];
      #pragma unroll
      for (int kc=0; kc<2; kc++)
        pf[kc] = *(const bf16x8*)&Pl[wid][c16*76 + kc*32 + g*8];

      // ---- PV : O += P * V ----
      #pragma unroll
      for (int dc=0; dc<8; dc++){
        int row = dc*16 + c16;
        int rsw = (c16 & 7) << 4;
        #pragma unroll
        for (int kc=0; kc<2; kc++){
          bf16x8 vf = *(const bf16x8*)((const char*)Vs[cur] + row*128 + ((kc*64 + g*16) ^ rsw));
          oacc[dc] = __builtin_amdgcn_mfma_f32_16x16x32_bf16(pf[kc], vf, oacc[dc], 0,0,0);
        }
      }

      __syncthreads();   // drains vmcnt (staging) + ensures all waves done reading cur
      cur ^= 1;
    }

    float inv[4];
    #pragma unroll
    for (int j=0;j<4;j++) inv[j] = 1.0f / lrun[j];
    #pragma unroll
    for (int dc=0; dc<8; dc++)
      #pragma unroll
      for (int j=0;j<4;j++)
        og[((size_t)(b*SS + qw + g*4 + j))*EE + h*DD + dc*16 + c16] = f2bf(oacc[dc][j]*inv[j]);
    __syncthreads();
  }
}

extern "C" void kernel_launch(void* const* d_in, const int* in_sizes, int n_in,
                              void* d_out, int out_size, void* d_ws, size_t ws_size,
                              hipStream_t stream){
  const float* x  = (const float*)d_in[0];
  const float* Wq = (const float*)d_in[1];
  const float* bq = (const float*)d_in[2];
  const float* Wk = (const float*)d_in[3];
  const float* bk = (const float*)d_in[4];
  const float* Wv = (const float*)d_in[5];
  const float* bv = (const float*)d_in[6];
  const float* Wp = (const float*)d_in[7];
  const float* bp = (const float*)d_in[8];
  float* out = (float*)d_out;

  char* ws = (char*)d_ws;
  size_t off = 0;
  auto alloc = [&](size_t bytes){ void* p = ws + off; off += (bytes + 255) & ~(size_t)255; return p; };
  const size_t nx = (size_t)MM*EE;
  const size_t nw = (size_t)EE*EE;
  __hip_bfloat16* xb  = (__hip_bfloat16*)alloc(nx*2);
  __hip_bfloat16* wqb = (__hip_bfloat16*)alloc(nw*2);
  __hip_bfloat16* wkb = (__hip_bfloat16*)alloc(nw*2);
  __hip_bfloat16* wvb = (__hip_bfloat16*)alloc(nw*2);
  __hip_bfloat16* wpb = (__hip_bfloat16*)alloc(nw*2);
  __hip_bfloat16* qb  = (__hip_bfloat16*)alloc(nx*2);
  __hip_bfloat16* kb  = (__hip_bfloat16*)alloc(nx*2);
  __hip_bfloat16* vtb = (__hip_bfloat16*)alloc(nx*2);
  __hip_bfloat16* ob  = (__hip_bfloat16*)alloc(nx*2);
  float* cost = (float*)alloc((size_t)SS*64*4);
  float* sint = (float*)alloc((size_t)SS*64*4);

  cvt_kernel<<<(int)(nx/4/256), 256, 0, stream>>>(x,  xb,  (int)(nx/4));
  cvt_kernel<<<(int)(nw/4/256), 256, 0, stream>>>(Wq, wqb, (int)(nw/4));
  cvt_kernel<<<(int)(nw/4/256), 256, 0, stream>>>(Wk, wkb, (int)(nw/4));
  cvt_kernel<<<(int)(nw/4/256), 256, 0, stream>>>(Wv, wvb, (int)(nw/4));
  cvt_kernel<<<(int)(nw/4/256), 256, 0, stream>>>(Wp, wpb, (int)(nw/4));
  rope_tables_kernel<<<SS*64/256, 256, 0, stream>>>(cost, sint);

  dim3 gg(MM/128, EE/128);
  gemm_bt<0><<<gg, 256, 0, stream>>>(xb, wqb, bq, qb);
  gemm_bt<0><<<gg, 256, 0, stream>>>(xb, wkb, bk, kb);
  gemm_bt<1><<<gg, 256, 0, stream>>>(xb, wvb, bv, vtb);

  rope_kernel<<<(BB*SS*HH*64)/256, 256, 0, stream>>>(qb, kb, cost, sint);

  attn_kernel<<<dim3(16, BB*HH), 256, 0, stream>>>(qb, kb, vtb, ob);

  gemm_bt<2><<<gg, 256, 0, stream>>>(ob, wpb, bp, out);
}

// Round 3
// 303.545 us; speedup vs baseline: 2.3275x; 1.0983x over previous
//
#include <hip/hip_runtime.h>
#include <hip/hip_bf16.h>
#include <math.h>

#define BB 2
#define SS 2048
#define EE 2048
#define HH 16
#define DD 128
#define MM (BB*SS)

typedef __attribute__((ext_vector_type(8))) short bf16x8;
typedef __attribute__((ext_vector_type(4))) float f32x4;

__device__ inline float bf2f(const __hip_bfloat16 h){ return __bfloat162float(h); }
__device__ inline __hip_bfloat16 f2bf(float f){ return __float2bfloat16(f); }
__device__ inline short f2bs(float f){
  union { __hip_bfloat16 h; short s; } u; u.h = __float2bfloat16(f); return u.s;
}

__device__ inline void gload16(const void* g, void* l){
  __builtin_amdgcn_global_load_lds((const __attribute__((address_space(1))) void*)g,
      (__attribute__((address_space(3))) void*)l, 16, 0, 0);
}

// ---------------- fp32 -> bf16 convert ----------------
__global__ void cvt_kernel(const float* __restrict__ in, __hip_bfloat16* __restrict__ out, int n4){
  int i = blockIdx.x*256 + threadIdx.x;
  if (i >= n4) return;
  float4 v = ((const float4*)in)[i];
  union { short4 s4; short s[4]; } u;
  u.s[0] = f2bs(v.x); u.s[1] = f2bs(v.y); u.s[2] = f2bs(v.z); u.s[3] = f2bs(v.w);
  ((short4*)out)[i] = u.s4;
}

struct P4 { const float* s0; const float* s1; const float* s2; const float* s3;
            __hip_bfloat16* d0; __hip_bfloat16* d1; __hip_bfloat16* d2; __hip_bfloat16* d3; };
__global__ void cvt4_kernel(P4 p, int n4){
  int w = blockIdx.y;
  const float* in = w==0 ? p.s0 : w==1 ? p.s1 : w==2 ? p.s2 : p.s3;
  __hip_bfloat16* out = w==0 ? p.d0 : w==1 ? p.d1 : w==2 ? p.d2 : p.d3;
  int i = blockIdx.x*256 + threadIdx.x;
  if (i >= n4) return;
  float4 v = ((const float4*)in)[i];
  union { short4 s4; short s[4]; } u;
  u.s[0] = f2bs(v.x); u.s[1] = f2bs(v.y); u.s[2] = f2bs(v.z); u.s[3] = f2bs(v.w);
  ((short4*)out)[i] = u.s4;
}

// ---------------- RoPE tables ----------------
__global__ void rope_tables_kernel(float* __restrict__ cost, float* __restrict__ sint){
  int idx = blockIdx.x*256 + threadIdx.x;  // SS*64
  int s = idx >> 6, i = idx & 63;
  double inv = exp(-log(10000.0) * (double)i / 64.0);
  double f = (double)s * inv;
  cost[idx] = (float)cos(f);
  sint[idx] = (float)sin(f);
}

// ---------------- RoPE apply on q,k (bf16, in place) ----------------
__global__ void rope_kernel(__hip_bfloat16* __restrict__ q, __hip_bfloat16* __restrict__ k,
                            const float* __restrict__ cost, const float* __restrict__ sint){
  int idx = blockIdx.x*256 + threadIdx.x;   // BB*SS*HH*64
  int i = idx & 63;
  int h = (idx >> 6) & (HH-1);
  int bs = idx >> 10;
  int s = bs & (SS-1);
  float c = cost[s*64 + i], sn = sint[s*64 + i];
  size_t base = ((size_t)bs*HH + h)*DD + i;
  float q1 = bf2f(q[base]), q2 = bf2f(q[base+64]);
  q[base]    = f2bf(q1*c - q2*sn);
  q[base+64] = f2bf(q2*c + q1*sn);
  float k1 = bf2f(k[base]), k2 = bf2f(k[base+64]);
  k[base]    = f2bf(k1*c - k2*sn);
  k[base+64] = f2bf(k2*c + k1*sn);
}

// ---------------- bf16 GEMM, 128x256 tile, BK=64, 8 waves, counted-vmcnt pipeline ----------------
// C[m][f] = sum_e A[m][e] * W[f][e] + bias[f]
// MODE 0: bf16 C[m*EE+f]; MODE 1: bf16 transposed vt[(b*EE+f)*SS+s]; MODE 2: fp32 C[m*EE+f]
template<int MODE>
__global__ __launch_bounds__(512) void gemm256(const __hip_bfloat16* __restrict__ A,
        const __hip_bfloat16* __restrict__ Bw, const float* __restrict__ bias,
        void* __restrict__ Cout){
  __shared__ __align__(1024) char lds[98304];   // 2 bufs x (A 16KB + B 32KB)
  const int tid = threadIdx.x, wid = tid>>6, lane = tid&63, g = lane>>4, c16 = lane&15;
  const int wm = wid>>2, wn = wid&3;
  // bijective XCD swizzle (nwg=256, 8 XCDs, q=32): XCD x owns N-column x
  const int orig = blockIdx.x;
  const int wg = (orig & 7)*32 + (orig >> 3);
  const int bm = wg & 31, bn = wg >> 5;
  const int rowA0 = bm*128, rowB0 = bn*256;
  const char* Ab8 = (const char*)A + (size_t)rowA0*4096;
  const char* Bb8 = (const char*)Bw + (size_t)rowB0*4096;

  f32x4 acc[4][4] = {};

  auto stage = [&](int t, int b){
    char* ad = lds + b*49152;
    char* bd = lds + b*49152 + 16384;
    #pragma unroll
    for (int i=0;i<2;i++){
      int off = i*8192 + tid*16;
      int r = off >> 7;
      int cs = (off & 127) ^ ((r&7)<<4);
      gload16(Ab8 + (size_t)r*4096 + t*128 + cs, ad + i*8192 + wid*1024);
    }
    #pragma unroll
    for (int i=0;i<4;i++){
      int off = i*8192 + tid*16;
      int r = off >> 7;
      int cs = (off & 127) ^ ((r&7)<<4);
      gload16(Bb8 + (size_t)r*4096 + t*128 + cs, bd + i*8192 + wid*1024);
    }
  };

  auto compute = [&](int b){
    const char* Abuf = lds + b*49152;
    const char* Bbuf = lds + b*49152 + 16384;
    bf16x8 bfr[4][2];
    #pragma unroll
    for (int ni=0;ni<4;ni++){
      int r = wn*64 + ni*16 + c16;
      int sw = (r&7)<<4;
      #pragma unroll
      for (int kk=0;kk<2;kk++)
        bfr[ni][kk] = *(const bf16x8*)(Bbuf + r*128 + ((kk*64 + g*16) ^ sw));
    }
    #pragma unroll
    for (int mi=0;mi<4;mi++){
      int r = wm*64 + mi*16 + c16;
      int sw = (r&7)<<4;
      bf16x8 af0 = *(const bf16x8*)(Abuf + r*128 + ((g*16) ^ sw));
      bf16x8 af1 = *(const bf16x8*)(Abuf + r*128 + ((64 + g*16) ^ sw));
      __builtin_amdgcn_s_setprio(1);
      #pragma unroll
      for (int ni=0;ni<4;ni++){
        acc[mi][ni] = __builtin_amdgcn_mfma_f32_16x16x32_bf16(af0, bfr[ni][0], acc[mi][ni],0,0,0);
        acc[mi][ni] = __builtin_amdgcn_mfma_f32_16x16x32_bf16(af1, bfr[ni][1], acc[mi][ni],0,0,0);
      }
      __builtin_amdgcn_s_setprio(0);
    }
  };

  // prologue: tiles 0 and 1 in flight; wait tile 0 (6 loads of tile 1 remain outstanding)
  stage(0,0);
  stage(1,1);
  asm volatile("s_waitcnt vmcnt(6)" ::: "memory");
  asm volatile("s_barrier" ::: "memory");

  #pragma unroll 1
  for (int tt = 0; tt < 32; tt += 2){
    compute(0);                                   // tile tt from buf0
    asm volatile("s_barrier" ::: "memory");       // all waves done reading buf0
    if (tt + 2 < 32){ stage(tt+2, 0); asm volatile("s_waitcnt vmcnt(6)" ::: "memory"); }
    else            {                 asm volatile("s_waitcnt vmcnt(0)" ::: "memory"); }
    asm volatile("s_barrier" ::: "memory");       // tile tt+1 visible to all
    compute(1);                                   // tile tt+1 from buf1
    if (tt + 2 < 32){
      asm volatile("s_barrier" ::: "memory");
      if (tt + 3 < 32){ stage(tt+3, 1); asm volatile("s_waitcnt vmcnt(6)" ::: "memory"); }
      else            {                 asm volatile("s_waitcnt vmcnt(0)" ::: "memory"); }
      asm volatile("s_barrier" ::: "memory");
    }
  }

  #pragma unroll
  for (int mi=0;mi<4;mi++){
    #pragma unroll
    for (int ni=0;ni<4;ni++){
      int f = rowB0 + wn*64 + ni*16 + c16;
      float bv = bias[f];
      #pragma unroll
      for (int j=0;j<4;j++){
        int m = rowA0 + wm*64 + mi*16 + g*4 + j;
        float v = acc[mi][ni][j] + bv;
        if constexpr (MODE == 0) {
          ((__hip_bfloat16*)Cout)[(size_t)m*EE + f] = f2bf(v);
        } else if constexpr (MODE == 1) {
          int b = m >> 11, s = m & (SS-1);
          ((__hip_bfloat16*)Cout)[((size_t)(b*EE + f))*SS + s] = f2bf(v);
        } else {
          ((float*)Cout)[(size_t)m*EE + f] = v;
        }
      }
    }
  }
}

// ---------------- flash attention (causal), 4 waves, QBLK=64, KVBLK=64 ----------------
__global__ __launch_bounds__(256) void attn_kernel(const __hip_bfloat16* __restrict__ qg,
    const __hip_bfloat16* __restrict__ kg, const __hip_bfloat16* __restrict__ vtg,
    __hip_bfloat16* __restrict__ og){
  __shared__ short Ks[2][64*128];
  __shared__ short Vs[2][128*64];
  __shared__ short Pl[4][16*76];
  const int tid=threadIdx.x, wid=tid>>6, lane=tid&63, g=lane>>4, c16=lane&15;
  const int bq = blockIdx.x, bh = blockIdx.y, b = bh>>4, h = bh&15;
  const char* kb8 = (const char*)(kg + ((size_t)b*SS)*EE + h*DD);
  const char* vb8 = (const char*)(vtg + (size_t)bh*DD*SS);
  const __hip_bfloat16* qbase = qg + ((size_t)b*SS)*EE + h*DD;
  const float SCL = 0.08838834764831845f * 1.4426950408889634f;

  #pragma unroll 1
  for (int t = 0; t < 2; ++t){
    const int qtile = t ? bq : (31 - bq);
    const int q0 = qtile*64, qw = q0 + wid*16;
    const int niter = qtile + 1;

    bf16x8 qf[4];
    #pragma unroll
    for (int ds=0; ds<4; ds++)
      qf[ds] = *(const bf16x8*)&qbase[(size_t)(qw + c16)*EE + ds*32 + g*8];

    f32x4 oacc[8] = {};
    float mrun[4], lrun[4];
    #pragma unroll
    for (int j=0;j<4;j++){ mrun[j] = -INFINITY; lrun[j] = 0.f; }

    #pragma unroll
    for (int i=0;i<4;i++){
      int base = i*4096 + wid*1024;
      int lb = base + lane*16;
      int r = lb >> 8, cb = lb & 255;
      gload16(kb8 + (size_t)r*4096 + (cb ^ ((r&7)<<4)), (char*)Ks[0] + base);
    }
    #pragma unroll
    for (int i=0;i<4;i++){
      int base = i*4096 + wid*1024;
      int lb = base + lane*16;
      int d = lb >> 7, cb = lb & 127;
      gload16(vb8 + (size_t)d*4096 + (cb ^ ((d&7)<<4)), (char*)Vs[0] + base);
    }
    __syncthreads();

    int cur = 0;
    #pragma unroll 1
    for (int it = 0; it < niter; ++it){
      const int kv0 = it*64;
      if (it + 1 < niter){
        const int kn = kv0 + 64;
        #pragma unroll
        for (int i=0;i<4;i++){
          int base = i*4096 + wid*1024;
          int lb = base + lane*16;
          int r = lb >> 8, cb = lb & 255;
          gload16(kb8 + (size_t)(kn + r)*4096 + (cb ^ ((r&7)<<4)), (char*)Ks[cur^1] + base);
        }
        #pragma unroll
        for (int i=0;i<4;i++){
          int base = i*4096 + wid*1024;
          int lb = base + lane*16;
          int d = lb >> 7, cb = lb & 127;
          gload16(vb8 + (size_t)d*4096 + (size_t)kn*2 + (cb ^ ((d&7)<<4)), (char*)Vs[cur^1] + base);
        }
      }

      f32x4 sacc[4] = {};
      #pragma unroll
      for (int kq=0; kq<4; kq++){
        int row = kq*16 + c16;
        int rsw = (c16 & 7) << 4;
        #pragma unroll
        for (int ds=0; ds<4; ds++){
          bf16x8 kf = *(const bf16x8*)((const char*)Ks[cur] + row*256 + ((ds*64 + g*16) ^ rsw));
          sacc[kq] = __builtin_amdgcn_mfma_f32_16x16x32_bf16(qf[ds], kf, sacc[kq], 0,0,0);
        }
      }

      if (kv0 + 63 > qw){
        #pragma unroll
        for (int kq=0; kq<4; kq++)
          #pragma unroll
          for (int j=0;j<4;j++)
            if (kv0 + kq*16 + c16 > qw + g*4 + j) sacc[kq][j] = -INFINITY;
      }

      float pr[4][4], rs[4];
      #pragma unroll
      for (int j=0;j<4;j++){
        float m = fmaxf(fmaxf(sacc[0][j], sacc[1][j]), fmaxf(sacc[2][j], sacc[3][j]));
        #pragma unroll
        for (int off=8; off>=1; off>>=1) m = fmaxf(m, __shfl_xor(m, off, 16));
        float mnew = fmaxf(mrun[j], m);
        rs[j] = exp2f((mrun[j] - mnew)*SCL);
        mrun[j] = mnew;
        float ps = 0.f;
        #pragma unroll
        for (int kq=0; kq<4; kq++){
          pr[kq][j] = exp2f((sacc[kq][j] - mnew)*SCL);
          ps += pr[kq][j];
        }
        #pragma unroll
        for (int off=8; off>=1; off>>=1) ps += __shfl_xor(ps, off, 16);
        lrun[j] = lrun[j]*rs[j] + ps;
      }
      #pragma unroll
      for (int dc=0; dc<8; dc++){
        f32x4 o = oacc[dc];
        o[0]*=rs[0]; o[1]*=rs[1]; o[2]*=rs[2]; o[3]*=rs[3];
        oacc[dc] = o;
      }

      #pragma unroll
      for (int j=0;j<4;j++)
        #pragma unroll
        for (int kq=0; kq<4; kq++)
          Pl[wid][(g*4+j)*76 + kq*16 + c16] = f2bs(pr[kq][j]);
      bf16x8 pf[2];
      #pragma unroll
      for (int kc=0; kc<2; kc++)
        pf[kc] = *(const bf16x8*)&Pl[wid][c16*76 + kc*32 + g*8];

      #pragma unroll
      for (int dc=0; dc<8; dc++){
        int row = dc*16 + c16;
        int rsw = (c16 & 7) << 4;
        #pragma unroll
        for (int kc=0; kc<2; kc++){
          bf16x8 vf = *(const bf16x8*)((const char*)Vs[cur] + row*128 + ((kc*64 + g*16) ^ rsw));
          oacc[dc] = __builtin_amdgcn_mfma_f32_16x16x32_bf16(pf[kc], vf, oacc[dc], 0,0,0);
        }
      }

      __syncthreads();
      cur ^= 1;
    }

    float inv[4];
    #pragma unroll
    for (int j=0;j<4;j++) inv[j] = 1.0f / lrun[j];
    #pragma unroll
    for (int dc=0; dc<8; dc++)
      #pragma unroll
      for (int j=0;j<4;j++)
        og[((size_t)(b*SS + qw + g*4 + j))*EE + h*DD + dc*16 + c16] = f2bf(oacc[dc][j]*inv[j]);
    __syncthreads();
  }
}

extern "C" void kernel_launch(void* const* d_in, const int* in_sizes, int n_in,
                              void* d_out, int out_size, void* d_ws, size_t ws_size,
                              hipStream_t stream){
  const float* x  = (const float*)d_in[0];
  const float* Wq = (const float*)d_in[1];
  const float* bq = (const float*)d_in[2];
  const float* Wk = (const float*)d_in[3];
  const float* bk = (const float*)d_in[4];
  const float* Wv = (const float*)d_in[5];
  const float* bv = (const float*)d_in[6];
  const float* Wp = (const float*)d_in[7];
  const float* bp = (const float*)d_in[8];
  float* out = (float*)d_out;

  char* ws = (char*)d_ws;
  size_t off = 0;
  auto alloc = [&](size_t bytes){ void* p = ws + off; off += (bytes + 255) & ~(size_t)255; return p; };
  const size_t nx = (size_t)MM*EE;
  const size_t nw = (size_t)EE*EE;
  __hip_bfloat16* xb  = (__hip_bfloat16*)alloc(nx*2);
  __hip_bfloat16* wqb = (__hip_bfloat16*)alloc(nw*2);
  __hip_bfloat16* wkb = (__hip_bfloat16*)alloc(nw*2);
  __hip_bfloat16* wvb = (__hip_bfloat16*)alloc(nw*2);
  __hip_bfloat16* wpb = (__hip_bfloat16*)alloc(nw*2);
  __hip_bfloat16* qb  = (__hip_bfloat16*)alloc(nx*2);
  __hip_bfloat16* kb  = (__hip_bfloat16*)alloc(nx*2);
  __hip_bfloat16* vtb = (__hip_bfloat16*)alloc(nx*2);
  __hip_bfloat16* ob  = (__hip_bfloat16*)alloc(nx*2);
  float* cost = (float*)alloc((size_t)SS*64*4);
  float* sint = (float*)alloc((size_t)SS*64*4);

  cvt_kernel<<<(int)(nx/4/256), 256, 0, stream>>>(x, xb, (int)(nx/4));
  P4 p4{Wq, Wk, Wv, Wp, wqb, wkb, wvb, wpb};
  cvt4_kernel<<<dim3((int)(nw/4/256), 4), 256, 0, stream>>>(p4, (int)(nw/4));
  rope_tables_kernel<<<SS*64/256, 256, 0, stream>>>(cost, sint);

  gemm256<0><<<256, 512, 0, stream>>>(xb, wqb, bq, qb);
  gemm256<0><<<256, 512, 0, stream>>>(xb, wkb, bk, kb);
  gemm256<1><<<256, 512, 0, stream>>>(xb, wvb, bv, vtb);

  rope_kernel<<<(BB*SS*HH*64)/256, 256, 0, stream>>>(qb, kb, cost, sint);

  attn_kernel<<<dim3(16, BB*HH), 256, 0, stream>>>(qb, kb, vtb, ob);

  gemm256<2><<<256, 512, 0, stream>>>(ob, wpb, bp, out);
}

// Round 4
// 284.558 us; speedup vs baseline: 2.4828x; 1.0667x over previous
//
#include <hip/hip_runtime.h>
#include <hip/hip_bf16.h>
#include <math.h>

#define BB 2
#define SS 2048
#define EE 2048
#define HH 16
#define DD 128
#define MM (BB*SS)

typedef __attribute__((ext_vector_type(8))) short bf16x8;
typedef __attribute__((ext_vector_type(4))) float f32x4;
typedef __attribute__((ext_vector_type(16))) float f32x16;
typedef __attribute__((ext_vector_type(4))) unsigned u32x4;

__device__ inline float bf2f(const __hip_bfloat16 h){ return __bfloat162float(h); }
__device__ inline __hip_bfloat16 f2bf(float f){ return __float2bfloat16(f); }
__device__ inline short f2bs(float f){
  union { __hip_bfloat16 h; short s; } u; u.h = __float2bfloat16(f); return u.s;
}
__device__ inline unsigned pk2(float a, float b){
  union { __hip_bfloat162 h2; unsigned u; } x;
  x.h2 = __float22bfloat162_rn(float2{a,b}); return x.u;   // low half = a
}

__device__ inline void gload16(const void* g, void* l){
  __builtin_amdgcn_global_load_lds((const __attribute__((address_space(1))) void*)g,
      (__attribute__((address_space(3))) void*)l, 16, 0, 0);
}

// ---------------- fp32 -> bf16 convert ----------------
__global__ void cvt_kernel(const float* __restrict__ in, __hip_bfloat16* __restrict__ out, int n4){
  int i = blockIdx.x*256 + threadIdx.x;
  if (i >= n4) return;
  float4 v = ((const float4*)in)[i];
  union { short4 s4; short s[4]; } u;
  u.s[0] = f2bs(v.x); u.s[1] = f2bs(v.y); u.s[2] = f2bs(v.z); u.s[3] = f2bs(v.w);
  ((short4*)out)[i] = u.s4;
}

struct P4 { const float* s0; const float* s1; const float* s2; const float* s3;
            __hip_bfloat16* d0; __hip_bfloat16* d1; __hip_bfloat16* d2; __hip_bfloat16* d3; };
__global__ void cvt4_kernel(P4 p, int n4){
  int w = blockIdx.y;
  const float* in = w==0 ? p.s0 : w==1 ? p.s1 : w==2 ? p.s2 : p.s3;
  __hip_bfloat16* out = w==0 ? p.d0 : w==1 ? p.d1 : w==2 ? p.d2 : p.d3;
  int i = blockIdx.x*256 + threadIdx.x;
  if (i >= n4) return;
  float4 v = ((const float4*)in)[i];
  union { short4 s4; short s[4]; } u;
  u.s[0] = f2bs(v.x); u.s[1] = f2bs(v.y); u.s[2] = f2bs(v.z); u.s[3] = f2bs(v.w);
  ((short4*)out)[i] = u.s4;
}

// ---------------- RoPE tables ----------------
__global__ void rope_tables_kernel(float* __restrict__ cost, float* __restrict__ sint){
  int idx = blockIdx.x*256 + threadIdx.x;  // SS*64
  int s = idx >> 6, i = idx & 63;
  double inv = exp(-log(10000.0) * (double)i / 64.0);
  double f = (double)s * inv;
  cost[idx] = (float)cos(f);
  sint[idx] = (float)sin(f);
}

// ---------------- RoPE apply on q,k (bf16, in place) ----------------
__global__ void rope_kernel(__hip_bfloat16* __restrict__ q, __hip_bfloat16* __restrict__ k,
                            const float* __restrict__ cost, const float* __restrict__ sint){
  int idx = blockIdx.x*256 + threadIdx.x;   // BB*SS*HH*64
  int i = idx & 63;
  int h = (idx >> 6) & (HH-1);
  int bs = idx >> 10;
  int s = bs & (SS-1);
  float c = cost[s*64 + i], sn = sint[s*64 + i];
  size_t base = ((size_t)bs*HH + h)*DD + i;
  float q1 = bf2f(q[base]), q2 = bf2f(q[base+64]);
  q[base]    = f2bf(q1*c - q2*sn);
  q[base+64] = f2bf(q2*c + q1*sn);
  float k1 = bf2f(k[base]), k2 = bf2f(k[base+64]);
  k[base]    = f2bf(k1*c - k2*sn);
  k[base+64] = f2bf(k2*c + k1*sn);
}

// ---------------- bf16 GEMM, 128x256 tile, BK=64, 8 waves, counted-vmcnt pipeline ----------------
template<int MODE>
__global__ __launch_bounds__(512) void gemm256(const __hip_bfloat16* __restrict__ A,
        const __hip_bfloat16* __restrict__ Bw, const float* __restrict__ bias,
        void* __restrict__ Cout){
  __shared__ __align__(1024) char lds[98304];
  const int tid = threadIdx.x, wid = tid>>6, lane = tid&63, g = lane>>4, c16 = lane&15;
  const int wm = wid>>2, wn = wid&3;
  const int orig = blockIdx.x;
  const int wg = (orig & 7)*32 + (orig >> 3);
  const int bm = wg & 31, bn = wg >> 5;
  const int rowA0 = bm*128, rowB0 = bn*256;
  const char* Ab8 = (const char*)A + (size_t)rowA0*4096;
  const char* Bb8 = (const char*)Bw + (size_t)rowB0*4096;

  f32x4 acc[4][4] = {};

  auto stage = [&](int t, int b){
    char* ad = lds + b*49152;
    char* bd = lds + b*49152 + 16384;
    #pragma unroll
    for (int i=0;i<2;i++){
      int off = i*8192 + tid*16;
      int r = off >> 7;
      int cs = (off & 127) ^ ((r&7)<<4);
      gload16(Ab8 + (size_t)r*4096 + t*128 + cs, ad + i*8192 + wid*1024);
    }
    #pragma unroll
    for (int i=0;i<4;i++){
      int off = i*8192 + tid*16;
      int r = off >> 7;
      int cs = (off & 127) ^ ((r&7)<<4);
      gload16(Bb8 + (size_t)r*4096 + t*128 + cs, bd + i*8192 + wid*1024);
    }
  };

  auto compute = [&](int b){
    const char* Abuf = lds + b*49152;
    const char* Bbuf = lds + b*49152 + 16384;
    bf16x8 bfr[4][2];
    #pragma unroll
    for (int ni=0;ni<4;ni++){
      int r = wn*64 + ni*16 + c16;
      int sw = (r&7)<<4;
      #pragma unroll
      for (int kk=0;kk<2;kk++)
        bfr[ni][kk] = *(const bf16x8*)(Bbuf + r*128 + ((kk*64 + g*16) ^ sw));
    }
    #pragma unroll
    for (int mi=0;mi<4;mi++){
      int r = wm*64 + mi*16 + c16;
      int sw = (r&7)<<4;
      bf16x8 af0 = *(const bf16x8*)(Abuf + r*128 + ((g*16) ^ sw));
      bf16x8 af1 = *(const bf16x8*)(Abuf + r*128 + ((64 + g*16) ^ sw));
      __builtin_amdgcn_s_setprio(1);
      #pragma unroll
      for (int ni=0;ni<4;ni++){
        acc[mi][ni] = __builtin_amdgcn_mfma_f32_16x16x32_bf16(af0, bfr[ni][0], acc[mi][ni],0,0,0);
        acc[mi][ni] = __builtin_amdgcn_mfma_f32_16x16x32_bf16(af1, bfr[ni][1], acc[mi][ni],0,0,0);
      }
      __builtin_amdgcn_s_setprio(0);
    }
  };

  stage(0,0);
  stage(1,1);
  asm volatile("s_waitcnt vmcnt(6)" ::: "memory");
  asm volatile("s_barrier" ::: "memory");

  #pragma unroll 1
  for (int tt = 0; tt < 32; tt += 2){
    compute(0);
    asm volatile("s_barrier" ::: "memory");
    if (tt + 2 < 32){ stage(tt+2, 0); asm volatile("s_waitcnt vmcnt(6)" ::: "memory"); }
    else            {                 asm volatile("s_waitcnt vmcnt(0)" ::: "memory"); }
    asm volatile("s_barrier" ::: "memory");
    compute(1);
    if (tt + 2 < 32){
      asm volatile("s_barrier" ::: "memory");
      if (tt + 3 < 32){ stage(tt+3, 1); asm volatile("s_waitcnt vmcnt(6)" ::: "memory"); }
      else            {                 asm volatile("s_waitcnt vmcnt(0)" ::: "memory"); }
      asm volatile("s_barrier" ::: "memory");
    }
  }

  #pragma unroll
  for (int mi=0;mi<4;mi++){
    #pragma unroll
    for (int ni=0;ni<4;ni++){
      int f = rowB0 + wn*64 + ni*16 + c16;
      float bv = bias[f];
      #pragma unroll
      for (int j=0;j<4;j++){
        int m = rowA0 + wm*64 + mi*16 + g*4 + j;
        float v = acc[mi][ni][j] + bv;
        if constexpr (MODE == 0) {
          ((__hip_bfloat16*)Cout)[(size_t)m*EE + f] = f2bf(v);
        } else if constexpr (MODE == 1) {
          int b = m >> 11, s = m & (SS-1);
          ((__hip_bfloat16*)Cout)[((size_t)(b*EE + f))*SS + s] = f2bf(v);
        } else {
          ((float*)Cout)[(size_t)m*EE + f] = v;
        }
      }
    }
  }
}

// ---------------- flash attention (causal), swapped-QK^T 32x32x16, 4 waves x 32q ----------------
// Each block: one (bh, qtile) with QBLK=128. Grid 512; ids i and i+256 carry
// complementary causal depths (land on same CU under linear dispatch -> balanced).
// S^T[kv][q] via mfma(K,Q): q = lane&31 -> softmax fully lane-local + 1 shfl_xor(32).
// P stays in registers; a 2-shfl exchange per kv-16 step builds the PV B-fragment.
__global__ __launch_bounds__(256, 2) void attn_kernel(const __hip_bfloat16* __restrict__ qg,
    const __hip_bfloat16* __restrict__ kg, const __hip_bfloat16* __restrict__ vtg,
    __hip_bfloat16* __restrict__ og){
  __shared__ short Ks[2][64*128];   // 16KB x2
  __shared__ short Vs[2][128*64];   // 16KB x2
  const int tid=threadIdx.x, wid=tid>>6, lane=tid&63;
  const int c32 = lane & 31, hi = lane >> 5;
  const int id = blockIdx.x;
  const int u = id & 255;
  const int bh = u & 31, pr = u >> 5;
  const int qtile = (id < 256) ? (15 - pr) : pr;
  const int b = bh >> 4, h = bh & 15;
  const int q0 = qtile*128, qw = q0 + wid*32;
  const int qglob = qw + c32;
  const int niter = 2*qtile + 2;

  const char* kb8 = (const char*)(kg + ((size_t)b*SS)*EE + h*DD);
  const char* vb8 = (const char*)(vtg + (size_t)bh*DD*SS);
  const float SCL = 0.08838834764831845f * 1.4426950408889634f;  // 1/sqrt(128)*log2(e)

  // Q row for this lane: 8 x bf16x8 covering d=0..127 (k = s*16 + hi*8)
  const char* qrow = (const char*)(qg + ((size_t)(b*SS + qglob))*EE + h*DD);
  bf16x8 qf[8];
  #pragma unroll
  for (int s=0;s<8;s++) qf[s] = *(const bf16x8*)(qrow + s*32 + hi*16);

  f32x16 pacc[4] = {};
  float mrun = -INFINITY, lrun = 0.f;

  auto stageK = [&](int kv, int buf){
    #pragma unroll
    for (int i=0;i<4;i++){
      int base = i*4096 + wid*1024;
      int lb = base + lane*16;
      int r = lb >> 8, cb = lb & 255;
      gload16(kb8 + (size_t)(kv + r)*4096 + (cb ^ ((r&7)<<4)), (char*)Ks[buf] + base);
    }
  };
  auto stageV = [&](int kv, int buf){
    #pragma unroll
    for (int i=0;i<4;i++){
      int base = i*4096 + wid*1024;
      int lb = base + lane*16;
      int d = lb >> 7, cb = lb & 127;
      gload16(vb8 + (size_t)d*4096 + (size_t)kv*2 + (cb ^ ((d&7)<<4)), (char*)Vs[buf] + base);
    }
  };

  stageK(0,0); stageV(0,0);
  __syncthreads();

  int cur = 0;
  #pragma unroll 1
  for (int it = 0; it < niter; ++it){
    const int kv0 = it*64;
    if (it + 1 < niter){ stageK(kv0+64, cur^1); stageV(kv0+64, cur^1); }

    // ---- QK^T: S^T[64kv x 32q], two 32-kv subtiles ----
    f32x16 st0 = {}, st1 = {};
    {
      const char* Kb = (const char*)Ks[cur];
      const int sw = (c32 & 7) << 4;
      #pragma unroll
      for (int s=0;s<8;s++){
        bf16x8 kf0 = *(const bf16x8*)(Kb + c32*256        + ((s*32 + hi*16) ^ sw));
        bf16x8 kf1 = *(const bf16x8*)(Kb + (32+c32)*256   + ((s*32 + hi*16) ^ sw));
        st0 = __builtin_amdgcn_mfma_f32_32x32x16_bf16(kf0, qf[s], st0, 0,0,0);
        st1 = __builtin_amdgcn_mfma_f32_32x32x16_bf16(kf1, qf[s], st1, 0,0,0);
      }
    }

    // ---- mask + in-register online softmax (q = lane column) ----
    float p[32];
    float vmax = -INFINITY;
    const bool domask = (kv0 + 63 > qw);
    #pragma unroll
    for (int r=0;r<16;r++){
      float v0 = st0[r], v1 = st1[r];
      if (domask){
        int kvo = (r&3) + 8*(r>>2) + 4*hi;
        if (kv0 + kvo > qglob)      v0 = -INFINITY;
        if (kv0 + 32 + kvo > qglob) v1 = -INFINITY;
      }
      p[r] = v0; p[16+r] = v1;
      vmax = fmaxf(vmax, fmaxf(v0, v1));
    }
    vmax = fmaxf(vmax, __shfl_xor(vmax, 32));
    const float mnew = fmaxf(mrun, vmax);
    const float rs = exp2f((mrun - mnew)*SCL);
    mrun = mnew;
    float ps = 0.f;
    #pragma unroll
    for (int i=0;i<32;i++){
      p[i] = exp2f((p[i] - mnew)*SCL);
      ps += p[i];
    }
    ps += __shfl_xor(ps, 32);
    lrun = lrun*rs + ps;

    // ---- rescale O ----
    #pragma unroll
    for (int ds=0; ds<4; ds++)
      #pragma unroll
      for (int r=0;r<16;r++) pacc[ds][r] *= rs;

    // ---- pack P to bf16 words: w[T][m][u] holds kv = 32T + 8m + 4hi + 2u ----
    unsigned w[2][4][2];
    #pragma unroll
    for (int T=0;T<2;T++)
      #pragma unroll
      for (int m=0;m<4;m++)
        #pragma unroll
        for (int uu=0;uu<2;uu++)
          w[T][m][uu] = pk2(p[T*16 + 4*m + 2*uu], p[T*16 + 4*m + 2*uu + 1]);

    // ---- build PV B-fragments: pf[ks] covers kv = 16ks + 8hi + 0..7 ----
    bf16x8 pf[4];
    #pragma unroll
    for (int ks=0; ks<4; ks++){
      int T = ks>>1, lo2 = (ks&1)*2;
      unsigned o0 = hi ? w[T][lo2+1][0] : w[T][lo2+0][0];
      unsigned o1 = hi ? w[T][lo2+1][1] : w[T][lo2+0][1];
      unsigned s0 = hi ? w[T][lo2+0][0] : w[T][lo2+1][0];
      unsigned s1 = hi ? w[T][lo2+0][1] : w[T][lo2+1][1];
      unsigned r0 = (unsigned)__shfl_xor((int)s0, 32);
      unsigned r1 = (unsigned)__shfl_xor((int)s1, 32);
      union { u32x4 u4; bf16x8 h8; } cvt;
      cvt.u4[0] = hi ? r0 : o0;
      cvt.u4[1] = hi ? r1 : o1;
      cvt.u4[2] = hi ? o0 : r0;
      cvt.u4[3] = hi ? o1 : r1;
      pf[ks] = cvt.h8;
    }

    // ---- PV: O^T[d][q] += Vt * P ----
    {
      const char* Vb = (const char*)Vs[cur];
      const int vsw = (c32 & 7) << 4;
      #pragma unroll
      for (int ds=0; ds<4; ds++){
        const char* vr = Vb + (ds*32 + c32)*128;
        #pragma unroll
        for (int ks=0; ks<4; ks++){
          bf16x8 vf = *(const bf16x8*)(vr + ((ks*32 + hi*16) ^ vsw));
          pacc[ds] = __builtin_amdgcn_mfma_f32_32x32x16_bf16(vf, pf[ks], pacc[ds], 0,0,0);
        }
      }
    }

    __syncthreads();
    cur ^= 1;
  }

  // ---- epilogue: O[q][d] = pacc^T / lrun ----
  const float invl = 1.0f / lrun;
  char* orow = (char*)(og + ((size_t)(b*SS + qglob))*EE + h*DD);
  #pragma unroll
  for (int ds=0; ds<4; ds++){
    #pragma unroll
    for (int m=0;m<4;m++){
      int d0 = ds*32 + 8*m + 4*hi;
      short4 s4;
      s4.x = f2bs(pacc[ds][4*m+0]*invl);
      s4.y = f2bs(pacc[ds][4*m+1]*invl);
      s4.z = f2bs(pacc[ds][4*m+2]*invl);
      s4.w = f2bs(pacc[ds][4*m+3]*invl);
      *(short4*)(orow + d0*2) = s4;
    }
  }
}

extern "C" void kernel_launch(void* const* d_in, const int* in_sizes, int n_in,
                              void* d_out, int out_size, void* d_ws, size_t ws_size,
                              hipStream_t stream){
  const float* x  = (const float*)d_in[0];
  const float* Wq = (const float*)d_in[1];
  const float* bq = (const float*)d_in[2];
  const float* Wk = (const float*)d_in[3];
  const float* bk = (const float*)d_in[4];
  const float* Wv = (const float*)d_in[5];
  const float* bv = (const float*)d_in[6];
  const float* Wp = (const float*)d_in[7];
  const float* bp = (const float*)d_in[8];
  float* out = (float*)d_out;

  char* ws = (char*)d_ws;
  size_t off = 0;
  auto alloc = [&](size_t bytes){ void* p = ws + off; off += (bytes + 255) & ~(size_t)255; return p; };
  const size_t nx = (size_t)MM*EE;
  const size_t nw = (size_t)EE*EE;
  __hip_bfloat16* xb  = (__hip_bfloat16*)alloc(nx*2);
  __hip_bfloat16* wqb = (__hip_bfloat16*)alloc(nw*2);
  __hip_bfloat16* wkb = (__hip_bfloat16*)alloc(nw*2);
  __hip_bfloat16* wvb = (__hip_bfloat16*)alloc(nw*2);
  __hip_bfloat16* wpb = (__hip_bfloat16*)alloc(nw*2);
  __hip_bfloat16* qb  = (__hip_bfloat16*)alloc(nx*2);
  __hip_bfloat16* kb  = (__hip_bfloat16*)alloc(nx*2);
  __hip_bfloat16* vtb = (__hip_bfloat16*)alloc(nx*2);
  __hip_bfloat16* ob  = (__hip_bfloat16*)alloc(nx*2);
  float* cost = (float*)alloc((size_t)SS*64*4);
  float* sint = (float*)alloc((size_t)SS*64*4);

  cvt_kernel<<<(int)(nx/4/256), 256, 0, stream>>>(x, xb, (int)(nx/4));
  P4 p4{Wq, Wk, Wv, Wp, wqb, wkb, wvb, wpb};
  cvt4_kernel<<<dim3((int)(nw/4/256), 4), 256, 0, stream>>>(p4, (int)(nw/4));
  rope_tables_kernel<<<SS*64/256, 256, 0, stream>>>(cost, sint);

  gemm256<0><<<256, 512, 0, stream>>>(xb, wqb, bq, qb);
  gemm256<0><<<256, 512, 0, stream>>>(xb, wkb, bk, kb);
  gemm256<1><<<256, 512, 0, stream>>>(xb, wvb, bv, vtb);

  rope_kernel<<<(BB*SS*HH*64)/256, 256, 0, stream>>>(qb, kb, cost, sint);

  attn_kernel<<<dim3(512), 256, 0, stream>>>(qb, kb, vtb, ob);

  gemm256<2><<<256, 512, 0, stream>>>(ob, wpb, bp, out);
}